// Round 1
// baseline (480.213 us; speedup 1.0000x reference)
//
#include <hip/hip_runtime.h>
#include <cfloat>

#define HH 64
#define WW 64
#define NKEYS 17
#define CCH 32
#define BG_W 10.0f

__device__ inline void wave_argmin(float &v, int &i) {
    #pragma unroll
    for (int off = 32; off > 0; off >>= 1) {
        float ov = __shfl_down(v, off, 64);
        int   oi = __shfl_down(i, off, 64);
        if (ov < v || (ov == v && oi < i)) { v = ov; i = oi; }
    }
}

__global__ __launch_bounds__(256) void ee_kernel(
    const float* __restrict__ kq,      // (B, C, H, W)
    const float* __restrict__ mkeys,   // (B, N, C)
    const int*   __restrict__ mjoints, // (B, N, 2)
    float* __restrict__ out_joints,    // (B, N, 2) as float
    float* __restrict__ out_valid,     // (B, N) as float
    float* __restrict__ out_keys,      // (B, N, C)
    float* __restrict__ out_x4)        // (B, N, 256, 256)
{
    const int bn  = blockIdx.x;
    const int b   = bn / NKEYS;
    const int tid = threadIdx.x;

    __shared__ float s_mk[CCH];
    __shared__ __align__(16) float s_wd[HH * WW];
    __shared__ float s_rv[4];
    __shared__ int   s_ri[4];

    if (tid < CCH) s_mk[tid] = mkeys[bn * CCH + tid];
    __syncthreads();

    // uniform across block: k2 and nonzero flag
    float k2 = 0.0f;
    bool  nz = false;
    #pragma unroll
    for (int c = 0; c < CCH; c++) {
        float v = s_mk[c];
        k2 += v * v;
        nz = nz || (v != 0.0f);
    }

    const int kpx = mjoints[bn * 2 + 0];
    const int kpy = mjoints[bn * 2 + 1];
    const int m_left  = max(kpx, 1);
    const int m_right = max(WW - 1 - kpx, 1);
    const int m_up    = max(kpy, 1);
    const int m_down  = max(HH - 1 - kpy, 1);

    const float4* kq4 = (const float4*)(kq + (size_t)b * CCH * HH * WW);

    float bestv = FLT_MAX;
    int   besti = 0;

    // ---- phase 1: weighted distance map into LDS + coarse argmin ----
    for (int j = 0; j < 4; j++) {
        const int chunk = tid + 256 * j;   // float4 chunk id, 0..1023
        float4 dot = make_float4(0.f, 0.f, 0.f, 0.f);
        float4 q2  = make_float4(0.f, 0.f, 0.f, 0.f);
        #pragma unroll
        for (int c = 0; c < CCH; c++) {
            float4 v = kq4[c * 1024 + chunk];
            float  m = s_mk[c];
            dot.x += v.x * m;  dot.y += v.y * m;
            dot.z += v.z * m;  dot.w += v.w * m;
            q2.x  += v.x * v.x; q2.y += v.y * v.y;
            q2.z  += v.z * v.z; q2.w += v.w * v.w;
        }
        float dots[4] = {dot.x, dot.y, dot.z, dot.w};
        float q2s[4]  = {q2.x,  q2.y,  q2.z,  q2.w};
        float4 wd;
        float* wdp = (float*)&wd;
        const int p0 = chunk * 4;
        #pragma unroll
        for (int k = 0; k < 4; k++) {
            const int p  = p0 + k;
            const int px = p & (WW - 1);
            const int py = p >> 6;
            float d2   = (q2s[k] + k2) - 2.0f * dots[k];
            float dist = sqrtf(fmaxf(d2, 0.0f));
            float wgt  = BG_W;
            #pragma unroll
            for (int m = 1; m <= 15; m++) {
                int xl = max(kpx - m, 0);
                int xr = min(kpx + m, WW - 1);
                int yu = max(kpy - m, 0);
                int yd = min(kpy + m, HH - 1);
                bool col = (((px == xl) && (m <= m_left)) || ((px == xr) && (m <= m_right)))
                           && (py >= yu) && (py <= yd);
                bool row = (((py == yu) && (m <= m_up)) || ((py == yd) && (m <= m_down)))
                           && (px >= xl) && (px <= xr);
                if (col || row) wgt = 0.5f + 0.25f * (float)m;
            }
            float wv = dist * wgt;
            wdp[k] = wv;
            if (wv < bestv) { bestv = wv; besti = p; }   // per-thread p ascending -> first occurrence
        }
        ((float4*)s_wd)[chunk] = wd;
    }

    // ---- coarse block argmin (lexicographic: val, then lower index) ----
    __syncthreads();
    wave_argmin(bestv, besti);
    if ((tid & 63) == 0) { s_rv[tid >> 6] = bestv; s_ri[tid >> 6] = besti; }
    __syncthreads();
    if (tid == 0) {
        float v = s_rv[0]; int i0 = s_ri[0];
        for (int w2 = 1; w2 < 4; w2++) {
            float ov = s_rv[w2]; int oi = s_ri[w2];
            if (ov < v || (ov == v && oi < i0)) { v = ov; i0 = oi; }
        }
        s_rv[0] = v; s_ri[0] = i0;
    }
    __syncthreads();
    const float min_d = s_rv[0];
    const int   cbest = s_ri[0];
    const bool  valid = nz && ((int)floorf(min_d) <= 5);

    if (tid < CCH) {
        float o = valid ? kq[(size_t)(b * CCH + tid) * (HH * WW) + cbest] : s_mk[tid];
        out_keys[bn * CCH + tid] = o;
    }

    // ---- phase 2: 4x bilinear upsample from LDS + fine argmin ----
    // x mapping for this thread (xo = tid): sample = (xo+0.5)/4 - 0.5
    const int xo = tid;
    const int rx = xo & 3;
    const int jx = xo >> 2;
    const int fx = jx + ((rx < 2) ? -1 : 0);
    const float txs[4] = {0.625f, 0.875f, 0.125f, 0.375f};
    const float tx  = txs[rx];
    const float wx0 = 1.0f - tx;
    const int cx0 = max(fx, 0);
    const int cx1 = min(fx + 1, WW - 1);
    const bool xe = (cx0 == cx1);   // edge: jax normalizes weights -> exact copy

    auto h_of = [&](int cy) -> float {
        float a = s_wd[cy * WW + cx0];
        if (xe) return a;
        float bb = s_wd[cy * WW + cx1];
        return wx0 * a + tx * bb;
    };

    float fbv = FLT_MAX;
    int   fbi = 0;
    float* xout = out_x4 + (size_t)bn * (256 * 256) + xo;

    float h_cur  = h_of(0);
    float h_prev = h_cur;   // clamped row -1
    for (int jy = 0; jy < 64; jy++) {
        float h_next = (jy < 63) ? h_of(jy + 1) : h_cur;
        // fine rows 4jy+r; r=0,1 use (jy-1,jy) with ty=0.625,0.875; r=2,3 use (jy,jy+1) with ty=0.125,0.375
        float v0 = (jy == 0)  ? h_cur : (0.375f * h_prev + 0.625f * h_cur);
        float v1 = (jy == 0)  ? h_cur : (0.125f * h_prev + 0.875f * h_cur);
        float v2 = (jy == 63) ? h_cur : (0.875f * h_cur + 0.125f * h_next);
        float v3 = (jy == 63) ? h_cur : (0.625f * h_cur + 0.375f * h_next);
        const int r0 = jy * 4;
        xout[(size_t)(r0 + 0) * 256] = v0;
        xout[(size_t)(r0 + 1) * 256] = v1;
        xout[(size_t)(r0 + 2) * 256] = v2;
        xout[(size_t)(r0 + 3) * 256] = v3;
        const int i0 = r0 * 256 + xo;
        if (v0 < fbv) { fbv = v0; fbi = i0; }
        if (v1 < fbv) { fbv = v1; fbi = i0 + 256; }
        if (v2 < fbv) { fbv = v2; fbi = i0 + 512; }
        if (v3 < fbv) { fbv = v3; fbi = i0 + 768; }
        h_prev = h_cur;
        h_cur  = h_next;
    }

    // ---- fine block argmin + scalar outputs ----
    wave_argmin(fbv, fbi);
    __syncthreads();   // protect s_rv/s_ri reuse
    if ((tid & 63) == 0) { s_rv[tid >> 6] = fbv; s_ri[tid >> 6] = fbi; }
    __syncthreads();
    if (tid == 0) {
        float v = s_rv[0]; int i0 = s_ri[0];
        for (int w2 = 1; w2 < 4; w2++) {
            float ov = s_rv[w2]; int oi = s_ri[w2];
            if (ov < v || (ov == v && oi < i0)) { v = ov; i0 = oi; }
        }
        int sv, sh;
        if (valid) { sv = i0 >> 8; sh = i0 & 255; }
        else       { sv = -1;      sh = -1;       }
        out_joints[bn * 2 + 0] = (float)sv;
        out_joints[bn * 2 + 1] = (float)sh;
        out_valid[bn] = valid ? 1.0f : 0.0f;
    }
}

extern "C" void kernel_launch(void* const* d_in, const int* in_sizes, int n_in,
                              void* d_out, int out_size, void* d_ws, size_t ws_size,
                              hipStream_t stream) {
    const float* kq = (const float*)d_in[0];
    const float* mk = (const float*)d_in[1];
    const int*   mj = (const int*)d_in[2];

    const int B = in_sizes[1] / (NKEYS * CCH);   // 64
    const int BN = B * NKEYS;                    // 1088

    float* out_f     = (float*)d_out;
    float* o_joints  = out_f;                    // B*N*2
    float* o_valid   = o_joints + BN * 2;        // B*N
    float* o_keys    = o_valid + BN;             // B*N*C
    float* o_x4      = o_keys + BN * CCH;        // B*N*256*256

    ee_kernel<<<dim3(BN), dim3(256), 0, stream>>>(kq, mk, mj, o_joints, o_valid, o_keys, o_x4);
}